// Round 1
// baseline (497.402 us; speedup 1.0000x reference)
//
#include <hip/hip_runtime.h>

#define NN 4096   // H*W
#define CC 256    // channels
#define DQ 32     // d_qk
#define NB 4      // batch

typedef float        f32x4 __attribute__((ext_vector_type(4)));
typedef short        s16x4 __attribute__((ext_vector_type(4)));
typedef unsigned int u32x2 __attribute__((ext_vector_type(2)));
typedef unsigned int u32x4 __attribute__((ext_vector_type(4)));

// float -> bf16 bits, round-to-nearest-even (header-version-proof)
__device__ __forceinline__ unsigned short f2bf(float f) {
  unsigned u = __builtin_bit_cast(unsigned, f);
  u += 0x7fffu + ((u >> 16) & 1u);
  return (unsigned short)(u >> 16);
}

__device__ __forceinline__ f32x4 mfma16(s16x4 a, s16x4 b, f32x4 c) {
  return __builtin_amdgcn_mfma_f32_16x16x16bf16_1k(a, b, c, 0, 0, 0);
}

__device__ __forceinline__ s16x4 lo4(u32x4 r) { u32x2 t = {r[0], r[1]}; return __builtin_bit_cast(s16x4, t); }
__device__ __forceinline__ s16x4 hi4(u32x4 r) { u32x2 t = {r[2], r[3]}; return __builtin_bit_cast(s16x4, t); }

#define XLS 264   // 256 + 8 pad (bf16) -> 528B row stride: <=2-way LDS bank aliasing (free)

// ---------------- Kernel A: fused QKV projection ----------------
// Out rows 0..31 -> Q (scale log2e/16 folded), 32..63 -> K, 64..319 -> V.
// QT/KT stored [B][N][32] bf16 (row-contiguous), V stored [B][C][N] bf16.
__global__ __launch_bounds__(256)
void proj_kernel(const float* __restrict__ x,
                 const float* __restrict__ Wq, const float* __restrict__ bq,
                 const float* __restrict__ Wk, const float* __restrict__ bk,
                 const float* __restrict__ Wv, const float* __restrict__ bv,
                 unsigned short* __restrict__ QT,
                 unsigned short* __restrict__ KT,
                 unsigned short* __restrict__ Vm) {
  __shared__ unsigned short Xl[64 * XLS];   // X^T tile: [n within 64][c 0..255]
  const int tid = threadIdx.x;
  const int b   = blockIdx.y;
  const int n0  = blockIdx.x * 64;

  // Stage X^T into LDS (coalesced float4 reads of x rows)
  {
    const int n4 = (tid & 15) * 4;
    int c = tid >> 4;
    const float* xp = x + (size_t)(b * CC + c) * NN + n0 + n4;
    #pragma unroll
    for (int it = 0; it < 16; ++it) {
      f32x4 v = *reinterpret_cast<const f32x4*>(xp);
      #pragma unroll
      for (int e = 0; e < 4; ++e)
        Xl[(n4 + e) * XLS + c] = f2bf(v[e]);
      c += 16; xp += (size_t)16 * NN;
    }
  }
  __syncthreads();

  const int wave = tid >> 6;
  const int lane = tid & 63;
  const int l16  = lane & 15;
  const int g    = lane >> 4;
  const float qscale = 0.0901684400555602f;  // log2(e)/16  (softmax scale folded into Q)

  // Each wave owns 5 row-tiles of 16 (320 rows total across 4 waves)
  const float* wrowp[5];
  float wsc[5];
  #pragma unroll
  for (int rt = 0; rt < 5; ++rt) {
    const int R0 = (wave * 5 + rt) * 16;
    const int R  = R0 + l16;
    if (R0 < 32)      { wrowp[rt] = Wq + R * CC;        wsc[rt] = qscale; }
    else if (R0 < 64) { wrowp[rt] = Wk + (R - 32) * CC; wsc[rt] = 1.0f; }
    else              { wrowp[rt] = Wv + (R - 64) * CC; wsc[rt] = 1.0f; }
  }

  f32x4 acc[5][4];
  #pragma unroll
  for (int rt = 0; rt < 5; ++rt)
    #pragma unroll
    for (int nt = 0; nt < 4; ++nt) acc[rt][nt] = (f32x4){0.f, 0.f, 0.f, 0.f};

  for (int k0 = 0; k0 < CC; k0 += 32) {
    s16x4 xb[4][2];
    #pragma unroll
    for (int nt = 0; nt < 4; ++nt) {
      const unsigned short* p = &Xl[(l16 + 16 * nt) * XLS + k0 + 8 * g];
      u32x4 raw = *reinterpret_cast<const u32x4*>(p);
      xb[nt][0] = lo4(raw);  // k-slots k0+8g+e   (consistent A/B permutation => correct)
      xb[nt][1] = hi4(raw);  // k-slots k0+8g+4+e
    }
    #pragma unroll
    for (int rt = 0; rt < 5; ++rt) {
      const float* wp = wrowp[rt] + k0 + 8 * g;
      f32x4 w0 = *reinterpret_cast<const f32x4*>(wp);
      f32x4 w1 = *reinterpret_cast<const f32x4*>(wp + 4);
      const float sc = wsc[rt];
      s16x4 wa0, wa1;
      #pragma unroll
      for (int e = 0; e < 4; ++e) {
        wa0[e] = (short)f2bf(w0[e] * sc);
        wa1[e] = (short)f2bf(w1[e] * sc);
      }
      #pragma unroll
      for (int nt = 0; nt < 4; ++nt) {
        acc[rt][nt] = mfma16(wa0, xb[nt][0], acc[rt][nt]);
        acc[rt][nt] = mfma16(wa1, xb[nt][1], acc[rt][nt]);
      }
    }
  }

  // Epilogue: +bias, write QT/KT packed 4x bf16 (8B), V scalar bf16
  #pragma unroll
  for (int rt = 0; rt < 5; ++rt) {
    const int R0 = (wave * 5 + rt) * 16;
    float bias_r[4];
    {
      const float* bp; float bsc;
      if (R0 < 32)      { bp = bq + R0;      bsc = qscale; }
      else if (R0 < 64) { bp = bk + R0 - 32; bsc = 1.0f; }
      else              { bp = bv + R0 - 64; bsc = 1.0f; }
      #pragma unroll
      for (int r = 0; r < 4; ++r) bias_r[r] = bp[4 * g + r] * bsc;
    }
    #pragma unroll
    for (int nt = 0; nt < 4; ++nt) {
      const int n = n0 + nt * 16 + l16;   // C-layout col = l16 (m89-verified)
      float v0 = acc[rt][nt][0] + bias_r[0];
      float v1 = acc[rt][nt][1] + bias_r[1];
      float v2 = acc[rt][nt][2] + bias_r[2];
      float v3 = acc[rt][nt][3] + bias_r[3];
      if (R0 < 64) {
        u32x2 pk = { (unsigned)f2bf(v0) | ((unsigned)f2bf(v1) << 16),
                     (unsigned)f2bf(v2) | ((unsigned)f2bf(v3) << 16) };
        unsigned short* dst = (R0 < 32)
          ? (QT + ((size_t)b * NN + n) * DQ + R0 + 4 * g)
          : (KT + ((size_t)b * NN + n) * DQ + (R0 - 32) + 4 * g);
        *reinterpret_cast<u32x2*>(dst) = pk;
      } else {
        const int c0 = R0 - 64 + 4 * g;   // C-layout row = 4g+reg
        Vm[((size_t)b * CC + c0 + 0) * NN + n] = f2bf(v0);
        Vm[((size_t)b * CC + c0 + 1) * NN + n] = f2bf(v1);
        Vm[((size_t)b * CC + c0 + 2) * NN + n] = f2bf(v2);
        Vm[((size_t)b * CC + c0 + 3) * NN + n] = f2bf(v3);
      }
    }
  }
}

// ---------------- Kernel B: flash attention (swapped S^T = K·Q^T) ----------------
// Block: 4 waves x 16 query rows = 64 rows. Each lane's S regs hold j-values of
// ONE query row (col=l16) -> softmax reduce is in-lane + 2 shfl_xor. S^T C-layout
// (row = 4g+reg) IS the 16x16x16 B-operand k-slot layout -> P feeds PV directly.
__global__ __launch_bounds__(256)
void attn_kernel(const unsigned short* __restrict__ QT,
                 const unsigned short* __restrict__ KT,
                 const unsigned short* __restrict__ Vm,
                 const float* __restrict__ x,
                 const float* __restrict__ gamma,
                 float* __restrict__ out) {
  const int tid  = threadIdx.x;
  const int wave = tid >> 6;
  const int lane = tid & 63;
  const int l16  = lane & 15;
  const int g    = lane >> 4;
  const int b    = blockIdx.y;
  const int i0   = blockIdx.x * 64 + wave * 16;
  const int i    = i0 + l16;

  // Q-frag (B operand of S^T), one 16B load; Q pre-scaled by log2e/16
  s16x4 qf0, qf1;
  {
    u32x4 qr = *reinterpret_cast<const u32x4*>(QT + ((size_t)b * NN + i) * DQ + 8 * g);
    qf0 = lo4(qr); qf1 = hi4(qr);
  }

  f32x4 o[16];  // O^T accumulator: 16 c-tiles x 4 rows, col = i (l16)
  #pragma unroll
  for (int t = 0; t < 16; ++t) o[t] = (f32x4){0.f, 0.f, 0.f, 0.f};
  float m_run = -__builtin_inff();
  float l_run = 0.f;

  const unsigned short* Kb = KT + (size_t)b * NN * DQ;
  const unsigned short* Vb = Vm + (size_t)b * CC * NN + (size_t)l16 * NN + 4 * g;

  for (int j0 = 0; j0 < NN; j0 += 32) {
    // S^T tiles: A = K rows (16B frag each), chained over k=32
    u32x4 kr1 = *reinterpret_cast<const u32x4*>(Kb + (size_t)(j0 + l16) * DQ + 8 * g);
    u32x4 kr2 = *reinterpret_cast<const u32x4*>(Kb + (size_t)(j0 + 16 + l16) * DQ + 8 * g);
    const f32x4 z = {0.f, 0.f, 0.f, 0.f};
    f32x4 s1 = mfma16(lo4(kr1), qf0, z);  s1 = mfma16(hi4(kr1), qf1, s1);
    f32x4 s2 = mfma16(lo4(kr2), qf0, z);  s2 = mfma16(hi4(kr2), qf1, s2);
    // s* are already in log2 domain (scale folded into Q)

    // tile max for this lane's query row: in-lane over 8, then across g axis
    float t = fmaxf(fmaxf(fmaxf(s1[0], s1[1]), fmaxf(s1[2], s1[3])),
                    fmaxf(fmaxf(s2[0], s2[1]), fmaxf(s2[2], s2[3])));
    t = fmaxf(t, __shfl_xor(t, 16));
    t = fmaxf(t, __shfl_xor(t, 32));

    if (__any(t > m_run)) {            // rare after first tiles (defer-style)
      const float m_new = fmaxf(m_run, t);
      const float alpha = exp2f(m_run - m_new);   // exp2(-inf)=0 on first tile
      l_run *= alpha;
      #pragma unroll
      for (int ct = 0; ct < 16; ++ct) {
        o[ct][0] *= alpha; o[ct][1] *= alpha; o[ct][2] *= alpha; o[ct][3] *= alpha;
      }
      m_run = m_new;
    }

    const float p0 = exp2f(s1[0] - m_run), p1 = exp2f(s1[1] - m_run);
    const float p2 = exp2f(s1[2] - m_run), p3 = exp2f(s1[3] - m_run);
    const float p4 = exp2f(s2[0] - m_run), p5 = exp2f(s2[1] - m_run);
    const float p6 = exp2f(s2[2] - m_run), p7 = exp2f(s2[3] - m_run);
    l_run += ((p0 + p1) + (p2 + p3)) + ((p4 + p5) + (p6 + p7));

    s16x4 pf1, pf2;   // P^T B-frags: slot (g,e) <-> j = 4g+e (+16), matches C-layout
    pf1[0] = (short)f2bf(p0); pf1[1] = (short)f2bf(p1);
    pf1[2] = (short)f2bf(p2); pf1[3] = (short)f2bf(p3);
    pf2[0] = (short)f2bf(p4); pf2[1] = (short)f2bf(p5);
    pf2[2] = (short)f2bf(p6); pf2[3] = (short)f2bf(p7);

    // PV: O^T[c][i] += V[c][j] * P^T[j][i]; A-frags are 8B loads from V rows
    const unsigned short* vp = Vb + j0;
    #pragma unroll
    for (int ct = 0; ct < 16; ++ct) {
      u32x2 va = *reinterpret_cast<const u32x2*>(vp + (size_t)ct * 16 * NN);
      u32x2 vb2 = *reinterpret_cast<const u32x2*>(vp + (size_t)ct * 16 * NN + 16);
      o[ct] = mfma16(__builtin_bit_cast(s16x4, va),  pf1, o[ct]);
      o[ct] = mfma16(__builtin_bit_cast(s16x4, vb2), pf2, o[ct]);
    }
  }

  // softmax denominator: reduce per-lane partials across the g axis
  float lt = l_run + __shfl_xor(l_run, 16);
  lt = lt + __shfl_xor(lt, 32);
  const float ga = gamma[0] / lt;

  #pragma unroll
  for (int ct = 0; ct < 16; ++ct) {
    #pragma unroll
    for (int r = 0; r < 4; ++r) {
      const int c = ct * 16 + 4 * g + r;
      const size_t adr = ((size_t)b * CC + c) * NN + i;
      out[adr] = ga * o[ct][r] + x[adr];   // residual in fp32
    }
  }
}

extern "C" void kernel_launch(void* const* d_in, const int* in_sizes, int n_in,
                              void* d_out, int out_size, void* d_ws, size_t ws_size,
                              hipStream_t stream) {
  const float* x     = (const float*)d_in[0];
  const float* Wq    = (const float*)d_in[1];
  const float* bq    = (const float*)d_in[2];
  const float* Wk    = (const float*)d_in[3];
  const float* bk    = (const float*)d_in[4];
  const float* Wv    = (const float*)d_in[5];
  const float* bv    = (const float*)d_in[6];
  const float* gamma = (const float*)d_in[7];
  float* out = (float*)d_out;

  // workspace: QT (1MB) | KT (1MB) | V (8MB), all bf16
  unsigned short* QT = (unsigned short*)d_ws;
  unsigned short* KT = QT + (size_t)NB * NN * DQ;
  unsigned short* Vm = KT + (size_t)NB * NN * DQ;

  dim3 grid(64, NB), blk(256);
  proj_kernel<<<grid, blk, 0, stream>>>(x, Wq, bq, Wk, bk, Wv, bv, QT, KT, Vm);
  attn_kernel<<<grid, blk, 0, stream>>>(QT, KT, Vm, x, gamma, out);
}

// Round 2
// 188.794 us; speedup vs baseline: 2.6346x; 2.6346x over previous
//
#include <hip/hip_runtime.h>

#define NN 4096   // H*W
#define CC 256    // channels
#define DQ 32     // d_qk
#define NB 4      // batch

typedef float        f32x4 __attribute__((ext_vector_type(4)));
typedef short        s16x4 __attribute__((ext_vector_type(4)));
typedef short        s16x8 __attribute__((ext_vector_type(8)));
typedef unsigned int u32x2 __attribute__((ext_vector_type(2)));
typedef unsigned int u32x4 __attribute__((ext_vector_type(4)));

// float -> bf16 bits, round-to-nearest-even
__device__ __forceinline__ unsigned short f2bf(float f) {
  unsigned u = __builtin_bit_cast(unsigned, f);
  u += 0x7fffu + ((u >> 16) & 1u);
  return (unsigned short)(u >> 16);
}

__device__ __forceinline__ f32x4 mfma16(s16x4 a, s16x4 b, f32x4 c) {
  return __builtin_amdgcn_mfma_f32_16x16x16bf16_1k(a, b, c, 0, 0, 0);
}
__device__ __forceinline__ f32x4 mfma32(s16x8 a, s16x8 b, f32x4 c) {
  return __builtin_amdgcn_mfma_f32_16x16x32_bf16(a, b, c, 0, 0, 0);
}

__device__ __forceinline__ s16x4 lo4(u32x4 r) { u32x2 t = {r[0], r[1]}; return __builtin_bit_cast(s16x4, t); }
__device__ __forceinline__ s16x4 hi4(u32x4 r) { u32x2 t = {r[2], r[3]}; return __builtin_bit_cast(s16x4, t); }
__device__ __forceinline__ s16x8 bc8(u32x4 r) { return __builtin_bit_cast(s16x8, r); }

#define XLS 264   // proj LDS row stride (256 + 8 pad)

// ---------------- Kernel A: fused QKV projection (unchanged, passed R1) ----------------
__global__ __launch_bounds__(256)
void proj_kernel(const float* __restrict__ x,
                 const float* __restrict__ Wq, const float* __restrict__ bq,
                 const float* __restrict__ Wk, const float* __restrict__ bk,
                 const float* __restrict__ Wv, const float* __restrict__ bv,
                 unsigned short* __restrict__ QT,
                 unsigned short* __restrict__ KT,
                 unsigned short* __restrict__ Vm) {
  __shared__ unsigned short Xl[64 * XLS];
  const int tid = threadIdx.x;
  const int b   = blockIdx.y;
  const int n0  = blockIdx.x * 64;

  {
    const int n4 = (tid & 15) * 4;
    int c = tid >> 4;
    const float* xp = x + (size_t)(b * CC + c) * NN + n0 + n4;
    #pragma unroll
    for (int it = 0; it < 16; ++it) {
      f32x4 v = *reinterpret_cast<const f32x4*>(xp);
      #pragma unroll
      for (int e = 0; e < 4; ++e)
        Xl[(n4 + e) * XLS + c] = f2bf(v[e]);
      c += 16; xp += (size_t)16 * NN;
    }
  }
  __syncthreads();

  const int wave = tid >> 6;
  const int lane = tid & 63;
  const int l16  = lane & 15;
  const int g    = lane >> 4;
  const float qscale = 0.0901684400555602f;  // log2(e)/16

  const float* wrowp[5];
  float wsc[5];
  #pragma unroll
  for (int rt = 0; rt < 5; ++rt) {
    const int R0 = (wave * 5 + rt) * 16;
    const int R  = R0 + l16;
    if (R0 < 32)      { wrowp[rt] = Wq + R * CC;        wsc[rt] = qscale; }
    else if (R0 < 64) { wrowp[rt] = Wk + (R - 32) * CC; wsc[rt] = 1.0f; }
    else              { wrowp[rt] = Wv + (R - 64) * CC; wsc[rt] = 1.0f; }
  }

  f32x4 acc[5][4];
  #pragma unroll
  for (int rt = 0; rt < 5; ++rt)
    #pragma unroll
    for (int nt = 0; nt < 4; ++nt) acc[rt][nt] = (f32x4){0.f, 0.f, 0.f, 0.f};

  for (int k0 = 0; k0 < CC; k0 += 32) {
    s16x4 xb[4][2];
    #pragma unroll
    for (int nt = 0; nt < 4; ++nt) {
      const unsigned short* p = &Xl[(l16 + 16 * nt) * XLS + k0 + 8 * g];
      u32x4 raw = *reinterpret_cast<const u32x4*>(p);
      xb[nt][0] = lo4(raw);
      xb[nt][1] = hi4(raw);
    }
    #pragma unroll
    for (int rt = 0; rt < 5; ++rt) {
      const float* wp = wrowp[rt] + k0 + 8 * g;
      f32x4 w0 = *reinterpret_cast<const f32x4*>(wp);
      f32x4 w1 = *reinterpret_cast<const f32x4*>(wp + 4);
      const float sc = wsc[rt];
      s16x4 wa0, wa1;
      #pragma unroll
      for (int e = 0; e < 4; ++e) {
        wa0[e] = (short)f2bf(w0[e] * sc);
        wa1[e] = (short)f2bf(w1[e] * sc);
      }
      #pragma unroll
      for (int nt = 0; nt < 4; ++nt) {
        acc[rt][nt] = mfma16(wa0, xb[nt][0], acc[rt][nt]);
        acc[rt][nt] = mfma16(wa1, xb[nt][1], acc[rt][nt]);
      }
    }
  }

  #pragma unroll
  for (int rt = 0; rt < 5; ++rt) {
    const int R0 = (wave * 5 + rt) * 16;
    float bias_r[4];
    {
      const float* bp; float bsc;
      if (R0 < 32)      { bp = bq + R0;      bsc = qscale; }
      else if (R0 < 64) { bp = bk + R0 - 32; bsc = 1.0f; }
      else              { bp = bv + R0 - 64; bsc = 1.0f; }
      #pragma unroll
      for (int r = 0; r < 4; ++r) bias_r[r] = bp[4 * g + r] * bsc;
    }
    #pragma unroll
    for (int nt = 0; nt < 4; ++nt) {
      const int n = n0 + nt * 16 + l16;
      float v0 = acc[rt][nt][0] + bias_r[0];
      float v1 = acc[rt][nt][1] + bias_r[1];
      float v2 = acc[rt][nt][2] + bias_r[2];
      float v3 = acc[rt][nt][3] + bias_r[3];
      if (R0 < 64) {
        u32x2 pk = { (unsigned)f2bf(v0) | ((unsigned)f2bf(v1) << 16),
                     (unsigned)f2bf(v2) | ((unsigned)f2bf(v3) << 16) };
        unsigned short* dst = (R0 < 32)
          ? (QT + ((size_t)b * NN + n) * DQ + R0 + 4 * g)
          : (KT + ((size_t)b * NN + n) * DQ + (R0 - 32) + 4 * g);
        *reinterpret_cast<u32x2*>(dst) = pk;
      } else {
        const int c0 = R0 - 64 + 4 * g;
        Vm[((size_t)b * CC + c0 + 0) * NN + n] = f2bf(v0);
        Vm[((size_t)b * CC + c0 + 1) * NN + n] = f2bf(v1);
        Vm[((size_t)b * CC + c0 + 2) * NN + n] = f2bf(v2);
        Vm[((size_t)b * CC + c0 + 3) * NN + n] = f2bf(v3);
      }
    }
  }
}

// ---------------- Kernel B: flash attention, LDS-staged V, x32 MFMA ----------------
#define RS 40                 // LDS row stride in bf16 elems (32 + 8 pad)

#define V_ISSUE(JP) { \
  const unsigned short* _s = Vbg + (size_t)cL * NN + (JP) + pcL * 8; \
  vst0 = *(const u32x4*)(_s); \
  vst1 = *(const u32x4*)(_s + (size_t)64  * NN); \
  vst2 = *(const u32x4*)(_s + (size_t)128 * NN); \
  vst3 = *(const u32x4*)(_s + (size_t)192 * NN); }

#define V_WRITE(BUF) { \
  *(u32x4*)&BUF[vwo]             = vst0; \
  *(u32x4*)&BUF[vwo +  64 * RS]  = vst1; \
  *(u32x4*)&BUF[vwo + 128 * RS]  = vst2; \
  *(u32x4*)&BUF[vwo + 192 * RS]  = vst3; }

#define K_ISSUE(JP, KA, KB) { \
  KA = *(const u32x4*)(Kbg + (size_t)((JP) + l16) * DQ + 8 * g); \
  KB = *(const u32x4*)(Kbg + (size_t)((JP) + 16 + l16) * DQ + 8 * g); }

// raw barrier: drain LDS ops but keep global prefetch loads in flight (no vmcnt drain)
#define BAR() { asm volatile("s_waitcnt lgkmcnt(0)" ::: "memory"); __builtin_amdgcn_s_barrier(); }

#define ITER(T, CUR, NXT, KA, KB) { \
  V_WRITE(NXT); /* compiler vmcnt-waits on vst*; writes buf retired by prev iter's 2nd barrier */ \
  f32x4 s1 = mfma32(bc8(KA), qf, zz); \
  f32x4 s2 = mfma32(bc8(KB), qf, zz); \
  { const int _jp = (((T) + 2 < 128) ? (T) + 2 : 127) * 32; \
    V_ISSUE(_jp); K_ISSUE(_jp, KA, KB); } \
  float tm = fmaxf(fmaxf(fmaxf(s1[0], s1[1]), fmaxf(s1[2], s1[3])), \
                   fmaxf(fmaxf(s2[0], s2[1]), fmaxf(s2[2], s2[3]))); \
  tm = fmaxf(tm, __shfl_xor(tm, 16)); \
  tm = fmaxf(tm, __shfl_xor(tm, 32)); \
  if (__any(tm > m_run)) { \
    const float m_new = fmaxf(m_run, tm); \
    const float alpha = exp2f(m_run - m_new); \
    l_run *= alpha; \
    _Pragma("unroll") \
    for (int ct = 0; ct < 16; ++ct) { \
      o[ct][0] *= alpha; o[ct][1] *= alpha; o[ct][2] *= alpha; o[ct][3] *= alpha; } \
    m_run = m_new; \
  } \
  const float p0 = exp2f(s1[0] - m_run), p1 = exp2f(s1[1] - m_run); \
  const float p2 = exp2f(s1[2] - m_run), p3 = exp2f(s1[3] - m_run); \
  const float p4 = exp2f(s2[0] - m_run), p5 = exp2f(s2[1] - m_run); \
  const float p6 = exp2f(s2[2] - m_run), p7 = exp2f(s2[3] - m_run); \
  l_run += ((p0 + p1) + (p2 + p3)) + ((p4 + p5) + (p6 + p7)); \
  s16x8 pf; \
  pf[0] = (short)f2bf(p0); pf[1] = (short)f2bf(p1); \
  pf[2] = (short)f2bf(p2); pf[3] = (short)f2bf(p3); \
  pf[4] = (short)f2bf(p4); pf[5] = (short)f2bf(p5); \
  pf[6] = (short)f2bf(p6); pf[7] = (short)f2bf(p7); \
  BAR(); /* NXT visible to all waves */ \
  _Pragma("unroll") \
  for (int ct = 0; ct < 16; ++ct) { \
    const unsigned short* _p = &CUR[(ct * 16 + l16) * RS + 4 * g]; \
    u32x2 _a = *(const u32x2*)(_p); \
    u32x2 _b = *(const u32x2*)(_p + 16); \
    u32x4 _t = {_a[0], _a[1], _b[0], _b[1]}; \
    o[ct] = mfma32(bc8(_t), pf, o[ct]); \
  } \
  BAR(); /* retire reads of CUR before next iter overwrites it */ \
}

__global__ __launch_bounds__(256)
void attn_kernel(const unsigned short* __restrict__ QT,
                 const unsigned short* __restrict__ KT,
                 const unsigned short* __restrict__ Vm,
                 const float* __restrict__ x,
                 const float* __restrict__ gamma,
                 float* __restrict__ out) {
  __shared__ unsigned short L0[256 * RS];
  __shared__ unsigned short L1[256 * RS];

  const int tid  = threadIdx.x;
  const int wave = tid >> 6;
  const int lane = tid & 63;
  const int l16  = lane & 15;
  const int g    = lane >> 4;

  // XCD-aware swizzle: gid%8 -> XCD (m09); give each XCD one batch (2 XCDs/batch)
  const int gid = blockIdx.y * gridDim.x + blockIdx.x;
  const int rr  = gid & 7;
  const int qq  = gid >> 3;
  const int b   = rr >> 1;
  const int xt  = (qq << 1) | (rr & 1);   // 0..63 row-tile within batch

  const int i0 = xt * 64 + wave * 16;
  const int i  = i0 + l16;

  s16x8 qf;
  {
    u32x4 qr = *reinterpret_cast<const u32x4*>(QT + ((size_t)b * NN + i) * DQ + 8 * g);
    qf = bc8(qr);
  }

  f32x4 o[16];
  #pragma unroll
  for (int t = 0; t < 16; ++t) o[t] = (f32x4){0.f, 0.f, 0.f, 0.f};
  float m_run = -__builtin_inff();
  float l_run = 0.f;
  const f32x4 zz = {0.f, 0.f, 0.f, 0.f};

  const unsigned short* Kbg = KT + (size_t)b * NN * DQ;
  const unsigned short* Vbg = Vm + (size_t)b * CC * NN;

  // V staging coords: thread -> (row cL, 16B piece pcL); 4 rounds of 64 rows
  const int cL  = tid >> 2;
  const int pcL = tid & 3;
  const int vwo = cL * RS + pcL * 8;

  u32x4 vst0, vst1, vst2, vst3;
  u32x4 kEa, kEb, kOa, kOb;

  // Prologue: tile0 -> L0; K0,K1 -> regs; tile1 loads in flight
  V_ISSUE(0);
  V_WRITE(L0);
  K_ISSUE(0,  kEa, kEb);
  K_ISSUE(32, kOa, kOb);
  V_ISSUE(32);
  BAR();

  #pragma unroll 1
  for (int tt = 0; tt < 64; ++tt) {
    ITER(2 * tt,     L0, L1, kEa, kEb);
    ITER(2 * tt + 1, L1, L0, kOa, kOb);
  }

  float lt = l_run + __shfl_xor(l_run, 16);
  lt = lt + __shfl_xor(lt, 32);
  const float ga = gamma[0] / lt;

  #pragma unroll
  for (int ct = 0; ct < 16; ++ct) {
    #pragma unroll
    for (int r = 0; r < 4; ++r) {
      const int c = ct * 16 + 4 * g + r;
      const size_t adr = ((size_t)b * CC + c) * NN + i;
      out[adr] = ga * o[ct][r] + x[adr];
    }
  }
}

extern "C" void kernel_launch(void* const* d_in, const int* in_sizes, int n_in,
                              void* d_out, int out_size, void* d_ws, size_t ws_size,
                              hipStream_t stream) {
  const float* x     = (const float*)d_in[0];
  const float* Wq    = (const float*)d_in[1];
  const float* bq    = (const float*)d_in[2];
  const float* Wk    = (const float*)d_in[3];
  const float* bk    = (const float*)d_in[4];
  const float* Wv    = (const float*)d_in[5];
  const float* bv    = (const float*)d_in[6];
  const float* gamma = (const float*)d_in[7];
  float* out = (float*)d_out;

  unsigned short* QT = (unsigned short*)d_ws;
  unsigned short* KT = QT + (size_t)NB * NN * DQ;
  unsigned short* Vm = KT + (size_t)NB * NN * DQ;

  dim3 grid(64, NB), blk(256);
  proj_kernel<<<grid, blk, 0, stream>>>(x, Wq, bq, Wk, bk, Wv, bv, QT, KT, Vm);
  attn_kernel<<<grid, blk, 0, stream>>>(QT, KT, Vm, x, gamma, out);
}

// Round 3
// 109.852 us; speedup vs baseline: 4.5279x; 1.7186x over previous
//
#include <hip/hip_runtime.h>

#define NN 4096   // H*W
#define CC 256    // channels
#define DQ 32     // d_qk
#define NB 4      // batch

typedef float        f32x4 __attribute__((ext_vector_type(4)));
typedef short        s16x4 __attribute__((ext_vector_type(4)));
typedef short        s16x8 __attribute__((ext_vector_type(8)));
typedef unsigned int u32x2 __attribute__((ext_vector_type(2)));
typedef unsigned int u32x4 __attribute__((ext_vector_type(4)));

// float -> bf16 bits, round-to-nearest-even
__device__ __forceinline__ unsigned short f2bf(float f) {
  unsigned u = __builtin_bit_cast(unsigned, f);
  u += 0x7fffu + ((u >> 16) & 1u);
  return (unsigned short)(u >> 16);
}

__device__ __forceinline__ f32x4 mfma16(s16x4 a, s16x4 b, f32x4 c) {
  return __builtin_amdgcn_mfma_f32_16x16x16bf16_1k(a, b, c, 0, 0, 0);
}
__device__ __forceinline__ f32x4 mfma32(s16x8 a, s16x8 b, f32x4 c) {
  return __builtin_amdgcn_mfma_f32_16x16x32_bf16(a, b, c, 0, 0, 0);
}

__device__ __forceinline__ s16x4 lo4(u32x4 r) { u32x2 t = {r[0], r[1]}; return __builtin_bit_cast(s16x4, t); }
__device__ __forceinline__ s16x4 hi4(u32x4 r) { u32x2 t = {r[2], r[3]}; return __builtin_bit_cast(s16x4, t); }
__device__ __forceinline__ s16x8 bc8(u32x4 r) { return __builtin_bit_cast(s16x8, r); }

#define XLS 264   // proj LDS row stride (256 + 8 pad)

// ---------------- Kernel A: fused QKV projection ----------------
// QT/KT: [B][N][32] bf16 row-contiguous.
// Vm   : TILED [B][jt=N/32][C][32] bf16, within-32 order = fragment k-slot
//        order {4g..4g+3, 16+4g..16+4g+3} so PV A-frags are single b128 reads.
__global__ __launch_bounds__(256)
void proj_kernel(const float* __restrict__ x,
                 const float* __restrict__ Wq, const float* __restrict__ bq,
                 const float* __restrict__ Wk, const float* __restrict__ bk,
                 const float* __restrict__ Wv, const float* __restrict__ bv,
                 unsigned short* __restrict__ QT,
                 unsigned short* __restrict__ KT,
                 unsigned short* __restrict__ Vm) {
  __shared__ unsigned short Xl[64 * XLS];
  const int tid = threadIdx.x;
  const int b   = blockIdx.y;
  const int n0  = blockIdx.x * 64;

  {
    const int n4 = (tid & 15) * 4;
    int c = tid >> 4;
    const float* xp = x + (size_t)(b * CC + c) * NN + n0 + n4;
    #pragma unroll
    for (int it = 0; it < 16; ++it) {
      f32x4 v = *reinterpret_cast<const f32x4*>(xp);
      #pragma unroll
      for (int e = 0; e < 4; ++e)
        Xl[(n4 + e) * XLS + c] = f2bf(v[e]);
      c += 16; xp += (size_t)16 * NN;
    }
  }
  __syncthreads();

  const int wave = tid >> 6;
  const int lane = tid & 63;
  const int l16  = lane & 15;
  const int g    = lane >> 4;
  const float qscale = 0.0901684400555602f;  // log2(e)/16

  const float* wrowp[5];
  float wsc[5];
  #pragma unroll
  for (int rt = 0; rt < 5; ++rt) {
    const int R0 = (wave * 5 + rt) * 16;
    const int R  = R0 + l16;
    if (R0 < 32)      { wrowp[rt] = Wq + R * CC;        wsc[rt] = qscale; }
    else if (R0 < 64) { wrowp[rt] = Wk + (R - 32) * CC; wsc[rt] = 1.0f; }
    else              { wrowp[rt] = Wv + (R - 64) * CC; wsc[rt] = 1.0f; }
  }

  f32x4 acc[5][4];
  #pragma unroll
  for (int rt = 0; rt < 5; ++rt)
    #pragma unroll
    for (int nt = 0; nt < 4; ++nt) acc[rt][nt] = (f32x4){0.f, 0.f, 0.f, 0.f};

  for (int k0 = 0; k0 < CC; k0 += 32) {
    s16x4 xb[4][2];
    #pragma unroll
    for (int nt = 0; nt < 4; ++nt) {
      const unsigned short* p = &Xl[(l16 + 16 * nt) * XLS + k0 + 8 * g];
      u32x4 raw = *reinterpret_cast<const u32x4*>(p);
      xb[nt][0] = lo4(raw);
      xb[nt][1] = hi4(raw);
    }
    #pragma unroll
    for (int rt = 0; rt < 5; ++rt) {
      const float* wp = wrowp[rt] + k0 + 8 * g;
      f32x4 w0 = *reinterpret_cast<const f32x4*>(wp);
      f32x4 w1 = *reinterpret_cast<const f32x4*>(wp + 4);
      const float sc = wsc[rt];
      s16x4 wa0, wa1;
      #pragma unroll
      for (int e = 0; e < 4; ++e) {
        wa0[e] = (short)f2bf(w0[e] * sc);
        wa1[e] = (short)f2bf(w1[e] * sc);
      }
      #pragma unroll
      for (int nt = 0; nt < 4; ++nt) {
        acc[rt][nt] = mfma16(wa0, xb[nt][0], acc[rt][nt]);
        acc[rt][nt] = mfma16(wa1, xb[nt][1], acc[rt][nt]);
      }
    }
  }

  #pragma unroll
  for (int rt = 0; rt < 5; ++rt) {
    const int R0 = (wave * 5 + rt) * 16;
    float bias_r[4];
    {
      const float* bp; float bsc;
      if (R0 < 32)      { bp = bq + R0;      bsc = qscale; }
      else if (R0 < 64) { bp = bk + R0 - 32; bsc = 1.0f; }
      else              { bp = bv + R0 - 64; bsc = 1.0f; }
      #pragma unroll
      for (int r = 0; r < 4; ++r) bias_r[r] = bp[4 * g + r] * bsc;
    }
    #pragma unroll
    for (int nt = 0; nt < 4; ++nt) {
      const int n = n0 + nt * 16 + l16;
      float v0 = acc[rt][nt][0] + bias_r[0];
      float v1 = acc[rt][nt][1] + bias_r[1];
      float v2 = acc[rt][nt][2] + bias_r[2];
      float v3 = acc[rt][nt][3] + bias_r[3];
      if (R0 < 64) {
        u32x2 pk = { (unsigned)f2bf(v0) | ((unsigned)f2bf(v1) << 16),
                     (unsigned)f2bf(v2) | ((unsigned)f2bf(v3) << 16) };
        unsigned short* dst = (R0 < 32)
          ? (QT + ((size_t)b * NN + n) * DQ + R0 + 4 * g)
          : (KT + ((size_t)b * NN + n) * DQ + (R0 - 32) + 4 * g);
        *reinterpret_cast<u32x2*>(dst) = pk;
      } else {
        // tiled V write: pos(j) = (j&3) + ((j>>2)&3)*8 + (j>=16 ? 4 : 0), j = 16*(nt&1)+l16
        const int c0  = R0 - 64 + 4 * g;
        const int jt  = (n0 + nt * 16) >> 5;
        const int pos = (l16 & 3) + ((l16 >> 2) << 3) + ((nt & 1) << 2);
        unsigned short* vd = Vm + ((size_t)(b * 128 + jt) * CC + c0) * 32 + pos;
        vd[0]  = f2bf(v0);
        vd[32] = f2bf(v1);
        vd[64] = f2bf(v2);
        vd[96] = f2bf(v3);
      }
    }
  }
}

// ---------------- Kernel B: flash attention, 8 waves = 4 strips x 2 j-halves ----------------
#define RS   40      // LDS row stride in bf16 elems (32 data + 8 pad) -> 80B
#define BUFE (256 * RS)

#define V_ISSUE(TL) { \
  const unsigned short* _s = Vbg + ((size_t)(jh * 64 + (TL)) * CC + cL) * 32 + pcL * 8; \
  vst0 = *(const u32x4*)(_s); \
  vst1 = *(const u32x4*)(_s + 64 * 32); \
  vst2 = *(const u32x4*)(_s + 128 * 32); \
  vst3 = *(const u32x4*)(_s + 192 * 32); }

#define V_WRITE(BUF) { \
  *(u32x4*)&(BUF)[vwo]            = vst0; \
  *(u32x4*)&(BUF)[vwo + 64 * RS]  = vst1; \
  *(u32x4*)&(BUF)[vwo + 128 * RS] = vst2; \
  *(u32x4*)&(BUF)[vwo + 192 * RS] = vst3; }

#define K_ISSUE(TL, KA, KB) { \
  const size_t _j0 = (size_t)(jh * 64 + (TL)) * 32; \
  KA = *(const u32x4*)(Kbg + (_j0 + l16) * DQ + 8 * g); \
  KB = *(const u32x4*)(Kbg + (_j0 + 16 + l16) * DQ + 8 * g); }

// raw barrier: drain LDS ops but keep global prefetch loads in flight
#define BAR() { asm volatile("s_waitcnt lgkmcnt(0)" ::: "memory"); __builtin_amdgcn_s_barrier(); }

#define ITER(TL, CUR, NXT, KA, KB) { \
  V_WRITE(NXT); \
  f32x4 s1 = mfma32(bc8(KA), qf, zz); \
  f32x4 s2 = mfma32(bc8(KB), qf, zz); \
  { const int _tp = ((TL) + 2 < 64) ? (TL) + 2 : 63; \
    V_ISSUE(_tp); K_ISSUE(_tp, KA, KB); } \
  float tm = fmaxf(fmaxf(fmaxf(fmaxf(s1[0], s1[1]), fmaxf(s1[2], s1[3])), \
                         fmaxf(fmaxf(s2[0], s2[1]), fmaxf(s2[2], s2[3]))), tmdummy); \
  tm = fmaxf(tm, __shfl_xor(tm, 16)); \
  tm = fmaxf(tm, __shfl_xor(tm, 32)); \
  if (__any(tm > m_run)) { \
    const float m_new = fmaxf(m_run, tm); \
    const float alpha = exp2f(m_run - m_new); \
    l_run *= alpha; \
    _Pragma("unroll") \
    for (int ct = 0; ct < 16; ++ct) { \
      o[ct][0] *= alpha; o[ct][1] *= alpha; o[ct][2] *= alpha; o[ct][3] *= alpha; } \
    m_run = m_new; \
  } \
  const float p0 = exp2f(s1[0] - m_run), p1 = exp2f(s1[1] - m_run); \
  const float p2 = exp2f(s1[2] - m_run), p3 = exp2f(s1[3] - m_run); \
  const float p4 = exp2f(s2[0] - m_run), p5 = exp2f(s2[1] - m_run); \
  const float p6 = exp2f(s2[2] - m_run), p7 = exp2f(s2[3] - m_run); \
  l_run += ((p0 + p1) + (p2 + p3)) + ((p4 + p5) + (p6 + p7)); \
  unsigned pk0, pk1, pk2, pk3; \
  asm("v_cvt_pk_bf16_f32 %0, %1, %2" : "=v"(pk0) : "v"(p0), "v"(p1)); \
  asm("v_cvt_pk_bf16_f32 %0, %1, %2" : "=v"(pk1) : "v"(p2), "v"(p3)); \
  asm("v_cvt_pk_bf16_f32 %0, %1, %2" : "=v"(pk2) : "v"(p4), "v"(p5)); \
  asm("v_cvt_pk_bf16_f32 %0, %1, %2" : "=v"(pk3) : "v"(p6), "v"(p7)); \
  u32x4 pkv = {pk0, pk1, pk2, pk3}; \
  s16x8 pf = bc8(pkv); \
  BAR(); /* NXT visible to group */ \
  _Pragma("unroll") \
  for (int ct = 0; ct < 16; ++ct) { \
    u32x4 _t = *(const u32x4*)&(CUR)[(ct * 16 + l16) * RS + 8 * g]; \
    o[ct] = mfma32(bc8(_t), pf, o[ct]); \
  } \
  BAR(); /* retire reads of CUR before overwrite */ \
}

__global__ __launch_bounds__(512)
void attn_kernel(const unsigned short* __restrict__ QT,
                 const unsigned short* __restrict__ KT,
                 const unsigned short* __restrict__ Vm,
                 const float* __restrict__ x,
                 const float* __restrict__ gamma,
                 float* __restrict__ out) {
  extern __shared__ unsigned short smem[];

  const int tid  = threadIdx.x;
  const int wave = tid >> 6;
  const int lane = tid & 63;
  const int l16  = lane & 15;
  const int g    = lane >> 4;
  const int jh   = wave >> 2;   // j-half: waves 0-3 tiles 0..63, waves 4-7 tiles 64..127
  const int s    = wave & 3;    // strip within block

  // XCD swizzle: gid%8 -> XCD; one batch per XCD pair
  const int gid = blockIdx.x;
  const int rr  = gid & 7;
  const int qq  = gid >> 3;
  const int b   = rr >> 1;
  const int xt  = (qq << 1) | (rr & 1);

  const int i = xt * 64 + s * 16 + l16;

  s16x8 qf = bc8(*reinterpret_cast<const u32x4*>(QT + ((size_t)b * NN + i) * DQ + 8 * g));

  f32x4 o[16];
  #pragma unroll
  for (int t = 0; t < 16; ++t) o[t] = (f32x4){0.f, 0.f, 0.f, 0.f};
  float m_run = -__builtin_inff();
  float l_run = 0.f;
  const f32x4 zz = {0.f, 0.f, 0.f, 0.f};
  const float tmdummy = -__builtin_inff();

  const unsigned short* Kbg = KT + (size_t)b * NN * DQ;
  const unsigned short* Vbg = Vm + (size_t)b * NN * CC;   // tiled base for batch

  // group-local staging coords: 256 threads stage 256 rows x 64B (4 b128 each)
  const int ltid = tid & 255;
  const int cL   = ltid >> 2;
  const int pcL  = ltid & 3;
  const int vwo  = cL * RS + pcL * 8;

  unsigned short* B0 = smem + (jh * 2 + 0) * BUFE;
  unsigned short* B1 = smem + (jh * 2 + 1) * BUFE;

  u32x4 vst0, vst1, vst2, vst3;
  u32x4 kEa, kEb, kOa, kOb;

  V_ISSUE(0);
  V_WRITE(B0);
  K_ISSUE(0, kEa, kEb);
  K_ISSUE(1, kOa, kOb);
  V_ISSUE(1);
  BAR();

  #pragma unroll 1
  for (int tt = 0; tt < 32; ++tt) {
    ITER(2 * tt,     B0, B1, kEa, kEb);
    ITER(2 * tt + 1, B1, B0, kOa, kOb);
  }

  // per-row full denominators
  float lt = l_run + __shfl_xor(l_run, 16);
  lt = lt + __shfl_xor(lt, 32);

  // ---- merge the two j-halves through LDS ----
  float* fb = (float*)smem;
  if (jh == 1) {
    f32x4* ob = (f32x4*)fb;
    #pragma unroll
    for (int ct = 0; ct < 16; ++ct)
      ob[(s * 16 + ct) * 64 + lane] = o[ct];
    fb[16384 + s * 64 + lane] = m_run;
    fb[16640 + s * 64 + lane] = lt;
  }
  BAR();
  if (jh == 0) {
    const float mB = fb[16384 + s * 64 + lane];
    const float lB = fb[16640 + s * 64 + lane];
    const float mS = fmaxf(m_run, mB);
    const float aA = exp2f(m_run - mS);
    const float aB = exp2f(mB - mS);
    const float lS = aA * lt + aB * lB;
    const float ga = gamma[0] / lS;
    const f32x4* ob = (const f32x4*)fb;
    #pragma unroll
    for (int ct = 0; ct < 16; ++ct) {
      f32x4 oB = ob[(s * 16 + ct) * 64 + lane];
      #pragma unroll
      for (int r = 0; r < 4; ++r) {
        const int c = ct * 16 + 4 * g + r;
        const size_t adr = ((size_t)b * CC + c) * NN + i;
        out[adr] = ga * (aA * o[ct][r] + aB * oB[r]) + x[adr];
      }
    }
  }
}

extern "C" void kernel_launch(void* const* d_in, const int* in_sizes, int n_in,
                              void* d_out, int out_size, void* d_ws, size_t ws_size,
                              hipStream_t stream) {
  const float* x     = (const float*)d_in[0];
  const float* Wq    = (const float*)d_in[1];
  const float* bq    = (const float*)d_in[2];
  const float* Wk    = (const float*)d_in[3];
  const float* bk    = (const float*)d_in[4];
  const float* Wv    = (const float*)d_in[5];
  const float* bv    = (const float*)d_in[6];
  const float* gamma = (const float*)d_in[7];
  float* out = (float*)d_out;

  unsigned short* QT = (unsigned short*)d_ws;
  unsigned short* KT = QT + (size_t)NB * NN * DQ;
  unsigned short* Vm = KT + (size_t)NB * NN * DQ;

  static bool attr_set = false;
  if (!attr_set) {
    hipFuncSetAttribute((const void*)attn_kernel,
                        hipFuncAttributeMaxDynamicSharedMemorySize, 4 * BUFE * 2);
    attr_set = true;
  }

  dim3 gridP(64, NB), blkP(256);
  proj_kernel<<<gridP, blkP, 0, stream>>>(x, Wq, bq, Wk, bk, Wv, bv, QT, KT, Vm);
  attn_kernel<<<256, 512, 4 * BUFE * 2, stream>>>(QT, KT, Vm, x, gamma, out);
}

// Round 4
// 97.228 us; speedup vs baseline: 5.1159x; 1.1298x over previous
//
#include <hip/hip_runtime.h>

#define NN 4096   // H*W
#define CC 256    // channels
#define DQ 32     // d_qk
#define NB 4      // batch

typedef float        f32x4 __attribute__((ext_vector_type(4)));
typedef short        s16x4 __attribute__((ext_vector_type(4)));
typedef short        s16x8 __attribute__((ext_vector_type(8)));
typedef unsigned int u32x2 __attribute__((ext_vector_type(2)));
typedef unsigned int u32x4 __attribute__((ext_vector_type(4)));

// float -> bf16 bits, round-to-nearest-even
__device__ __forceinline__ unsigned short f2bf(float f) {
  unsigned u = __builtin_bit_cast(unsigned, f);
  u += 0x7fffu + ((u >> 16) & 1u);
  return (unsigned short)(u >> 16);
}

__device__ __forceinline__ f32x4 mfma16(s16x4 a, s16x4 b, f32x4 c) {
  return __builtin_amdgcn_mfma_f32_16x16x16bf16_1k(a, b, c, 0, 0, 0);
}
__device__ __forceinline__ f32x4 mfma32(s16x8 a, s16x8 b, f32x4 c) {
  return __builtin_amdgcn_mfma_f32_16x16x32_bf16(a, b, c, 0, 0, 0);
}

__device__ __forceinline__ s16x4 lo4(u32x4 r) { u32x2 t = {r[0], r[1]}; return __builtin_bit_cast(s16x4, t); }
__device__ __forceinline__ s16x4 hi4(u32x4 r) { u32x2 t = {r[2], r[3]}; return __builtin_bit_cast(s16x4, t); }
__device__ __forceinline__ s16x8 bc8(u32x4 r) { return __builtin_bit_cast(s16x8, r); }

#define XLS 264   // proj LDS row stride (256 + 8 pad)

// ---------------- Kernel A: fused QKV projection (unchanged since R2) ----------------
// QT/KT: [B][N][32] bf16 row-contiguous.
// Vm   : TILED [B][jt=N/32][C][32] bf16, within-32 order = fragment k-slot order.
__global__ __launch_bounds__(256)
void proj_kernel(const float* __restrict__ x,
                 const float* __restrict__ Wq, const float* __restrict__ bq,
                 const float* __restrict__ Wk, const float* __restrict__ bk,
                 const float* __restrict__ Wv, const float* __restrict__ bv,
                 unsigned short* __restrict__ QT,
                 unsigned short* __restrict__ KT,
                 unsigned short* __restrict__ Vm) {
  __shared__ unsigned short Xl[64 * XLS];
  const int tid = threadIdx.x;
  const int b   = blockIdx.y;
  const int n0  = blockIdx.x * 64;

  {
    const int n4 = (tid & 15) * 4;
    int c = tid >> 4;
    const float* xp = x + (size_t)(b * CC + c) * NN + n0 + n4;
    #pragma unroll
    for (int it = 0; it < 16; ++it) {
      f32x4 v = *reinterpret_cast<const f32x4*>(xp);
      #pragma unroll
      for (int e = 0; e < 4; ++e)
        Xl[(n4 + e) * XLS + c] = f2bf(v[e]);
      c += 16; xp += (size_t)16 * NN;
    }
  }
  __syncthreads();

  const int wave = tid >> 6;
  const int lane = tid & 63;
  const int l16  = lane & 15;
  const int g    = lane >> 4;
  const float qscale = 0.0901684400555602f;  // log2(e)/16

  const float* wrowp[5];
  float wsc[5];
  #pragma unroll
  for (int rt = 0; rt < 5; ++rt) {
    const int R0 = (wave * 5 + rt) * 16;
    const int R  = R0 + l16;
    if (R0 < 32)      { wrowp[rt] = Wq + R * CC;        wsc[rt] = qscale; }
    else if (R0 < 64) { wrowp[rt] = Wk + (R - 32) * CC; wsc[rt] = 1.0f; }
    else              { wrowp[rt] = Wv + (R - 64) * CC; wsc[rt] = 1.0f; }
  }

  f32x4 acc[5][4];
  #pragma unroll
  for (int rt = 0; rt < 5; ++rt)
    #pragma unroll
    for (int nt = 0; nt < 4; ++nt) acc[rt][nt] = (f32x4){0.f, 0.f, 0.f, 0.f};

  for (int k0 = 0; k0 < CC; k0 += 32) {
    s16x4 xb[4][2];
    #pragma unroll
    for (int nt = 0; nt < 4; ++nt) {
      const unsigned short* p = &Xl[(l16 + 16 * nt) * XLS + k0 + 8 * g];
      u32x4 raw = *reinterpret_cast<const u32x4*>(p);
      xb[nt][0] = lo4(raw);
      xb[nt][1] = hi4(raw);
    }
    #pragma unroll
    for (int rt = 0; rt < 5; ++rt) {
      const float* wp = wrowp[rt] + k0 + 8 * g;
      f32x4 w0 = *reinterpret_cast<const f32x4*>(wp);
      f32x4 w1 = *reinterpret_cast<const f32x4*>(wp + 4);
      const float sc = wsc[rt];
      s16x4 wa0, wa1;
      #pragma unroll
      for (int e = 0; e < 4; ++e) {
        wa0[e] = (short)f2bf(w0[e] * sc);
        wa1[e] = (short)f2bf(w1[e] * sc);
      }
      #pragma unroll
      for (int nt = 0; nt < 4; ++nt) {
        acc[rt][nt] = mfma16(wa0, xb[nt][0], acc[rt][nt]);
        acc[rt][nt] = mfma16(wa1, xb[nt][1], acc[rt][nt]);
      }
    }
  }

  #pragma unroll
  for (int rt = 0; rt < 5; ++rt) {
    const int R0 = (wave * 5 + rt) * 16;
    float bias_r[4];
    {
      const float* bp; float bsc;
      if (R0 < 32)      { bp = bq + R0;      bsc = qscale; }
      else if (R0 < 64) { bp = bk + R0 - 32; bsc = 1.0f; }
      else              { bp = bv + R0 - 64; bsc = 1.0f; }
      #pragma unroll
      for (int r = 0; r < 4; ++r) bias_r[r] = bp[4 * g + r] * bsc;
    }
    #pragma unroll
    for (int nt = 0; nt < 4; ++nt) {
      const int n = n0 + nt * 16 + l16;
      float v0 = acc[rt][nt][0] + bias_r[0];
      float v1 = acc[rt][nt][1] + bias_r[1];
      float v2 = acc[rt][nt][2] + bias_r[2];
      float v3 = acc[rt][nt][3] + bias_r[3];
      if (R0 < 64) {
        u32x2 pk = { (unsigned)f2bf(v0) | ((unsigned)f2bf(v1) << 16),
                     (unsigned)f2bf(v2) | ((unsigned)f2bf(v3) << 16) };
        unsigned short* dst = (R0 < 32)
          ? (QT + ((size_t)b * NN + n) * DQ + R0 + 4 * g)
          : (KT + ((size_t)b * NN + n) * DQ + (R0 - 32) + 4 * g);
        *reinterpret_cast<u32x2*>(dst) = pk;
      } else {
        const int c0  = R0 - 64 + 4 * g;
        const int jt  = (n0 + nt * 16) >> 5;
        const int pos = (l16 & 3) + ((l16 >> 2) << 3) + ((nt & 1) << 2);
        unsigned short* vd = Vm + ((size_t)(b * 128 + jt) * CC + c0) * 32 + pos;
        vd[0]  = f2bf(v0);
        vd[32] = f2bf(v1);
        vd[64] = f2bf(v2);
        vd[96] = f2bf(v3);
      }
    }
  }
}

// ---------------- Kernel B: flash attention ----------------
// 8 waves = 2 strips(32 q-rows) x 2 c-halves(128 ch) x 2 j-halves.
// Per wave per j-tile: 4 QK MFMA + 8 ds_read_b128 + 16 PV MFMA + 2 lsum MFMA.
// Defer-max (m init 8, trigger ~never) -> no per-tile shuffles.
// 3-buffer rotation -> 1 barrier per tile.
#define RS   40      // LDS row stride in bf16 elems (32 data + 8 pad)
#define BUFE (256 * RS)

#define V_ISSUE(TL) { \
  const unsigned short* _s = Vbg + ((size_t)(jh * 64 + (TL)) * CC + cL) * 32 + pcL * 8; \
  vst0 = *(const u32x4*)(_s); \
  vst1 = *(const u32x4*)(_s + 64 * 32); \
  vst2 = *(const u32x4*)(_s + 128 * 32); \
  vst3 = *(const u32x4*)(_s + 192 * 32); }

#define V_WRITE(BUF) { \
  *(u32x4*)&(BUF)[vwo]            = vst0; \
  *(u32x4*)&(BUF)[vwo + 64 * RS]  = vst1; \
  *(u32x4*)&(BUF)[vwo + 128 * RS] = vst2; \
  *(u32x4*)&(BUF)[vwo + 192 * RS] = vst3; }

#define K_ISSUE(TL, KA, KB) { \
  const size_t _j0 = (size_t)(jh * 64 + (TL)) * 32; \
  KA = *(const u32x4*)(Kbg + (_j0 + l16) * DQ + 8 * g); \
  KB = *(const u32x4*)(Kbg + (_j0 + 16 + l16) * DQ + 8 * g); }

// raw barrier: drain LDS ops, keep global prefetch loads in flight
#define BAR() { asm volatile("s_waitcnt lgkmcnt(0)" ::: "memory"); __builtin_amdgcn_s_barrier(); }

#define SM_HALF(SA, SB, M, PF) { \
  const float p0 = exp2f(SA[0] - M), p1 = exp2f(SA[1] - M); \
  const float p2 = exp2f(SA[2] - M), p3 = exp2f(SA[3] - M); \
  const float p4 = exp2f(SB[0] - M), p5 = exp2f(SB[1] - M); \
  const float p6 = exp2f(SB[2] - M), p7 = exp2f(SB[3] - M); \
  unsigned pk0, pk1, pk2, pk3; \
  asm("v_cvt_pk_bf16_f32 %0, %1, %2" : "=v"(pk0) : "v"(p0), "v"(p1)); \
  asm("v_cvt_pk_bf16_f32 %0, %1, %2" : "=v"(pk1) : "v"(p2), "v"(p3)); \
  asm("v_cvt_pk_bf16_f32 %0, %1, %2" : "=v"(pk2) : "v"(p4), "v"(p5)); \
  asm("v_cvt_pk_bf16_f32 %0, %1, %2" : "=v"(pk3) : "v"(p6), "v"(p7)); \
  u32x4 _pkv = {pk0, pk1, pk2, pk3}; \
  PF = bc8(_pkv); }

#define ITER(TL, CUR, NXT, KA, KB) { \
  V_WRITE(NXT); \
  f32x4 s00 = mfma32(bc8(KA), qf0, zz); \
  f32x4 s01 = mfma32(bc8(KB), qf0, zz); \
  f32x4 s10 = mfma32(bc8(KA), qf1, zz); \
  f32x4 s11 = mfma32(bc8(KB), qf1, zz); \
  { const int _tp = ((TL) + 2 < 64) ? (TL) + 2 : 63; V_ISSUE(_tp); } \
  { const int _tk = ((TL) + 3 < 64) ? (TL) + 3 : 63; K_ISSUE(_tk, KA, KB); } \
  float tm0 = fmaxf(fmaxf(fmaxf(s00[0], s00[1]), fmaxf(s00[2], s00[3])), \
                    fmaxf(fmaxf(s01[0], s01[1]), fmaxf(s01[2], s01[3]))); \
  float tm1 = fmaxf(fmaxf(fmaxf(s10[0], s10[1]), fmaxf(s10[2], s10[3])), \
                    fmaxf(fmaxf(s11[0], s11[1]), fmaxf(s11[2], s11[3]))); \
  if (__any((tm0 > m0) || (tm1 > m1))) {   /* ~never fires: scores << 8 */ \
    tm0 = fmaxf(tm0, __shfl_xor(tm0, 16)); tm0 = fmaxf(tm0, __shfl_xor(tm0, 32)); \
    tm1 = fmaxf(tm1, __shfl_xor(tm1, 16)); tm1 = fmaxf(tm1, __shfl_xor(tm1, 32)); \
    const float mn0 = fmaxf(m0, tm0), mn1 = fmaxf(m1, tm1); \
    const float a0 = exp2f(m0 - mn0), a1 = exp2f(m1 - mn1); \
    _Pragma("unroll") \
    for (int ct = 0; ct < 8; ++ct) { \
      _Pragma("unroll") \
      for (int r = 0; r < 4; ++r) { o[ct][0][r] *= a0; o[ct][1][r] *= a1; } \
    } \
    _Pragma("unroll") \
    for (int r = 0; r < 4; ++r) { lsum0[r] *= a0; lsum1[r] *= a1; } \
    m0 = mn0; m1 = mn1; \
  } \
  s16x8 pf0, pf1; \
  SM_HALF(s00, s01, m0, pf0); \
  SM_HALF(s10, s11, m1, pf1); \
  lsum0 = mfma32(ones8, pf0, lsum0); \
  lsum1 = mfma32(ones8, pf1, lsum1); \
  _Pragma("unroll") \
  for (int ct = 0; ct < 8; ++ct) { \
    u32x4 _vf = *(const u32x4*)&(CUR)[(chv * 128 + ct * 16 + l16) * RS + 8 * g]; \
    o[ct][0] = mfma32(bc8(_vf), pf0, o[ct][0]); \
    o[ct][1] = mfma32(bc8(_vf), pf1, o[ct][1]); \
  } \
  BAR(); \
}

__global__ __launch_bounds__(512)
void attn_kernel(const unsigned short* __restrict__ QT,
                 const unsigned short* __restrict__ KT,
                 const unsigned short* __restrict__ Vm,
                 const float* __restrict__ x,
                 const float* __restrict__ gamma,
                 float* __restrict__ out) {
  extern __shared__ unsigned short smem[];

  const int tid  = threadIdx.x;
  const int wave = tid >> 6;
  const int lane = tid & 63;
  const int l16  = lane & 15;
  const int g    = lane >> 4;
  const int jh   = wave >> 2;        // j-half
  const int s    = (wave >> 1) & 1;  // strip (32 q-rows)
  const int chv  = wave & 1;         // channel half (128 ch)

  // XCD swizzle: gid%8 -> XCD; one batch per XCD pair
  const int gid = blockIdx.x;
  const int rr  = gid & 7;
  const int qq  = gid >> 3;
  const int b   = rr >> 1;
  const int xt  = (qq << 1) | (rr & 1);

  const int ibase = xt * 64 + s * 32;
  const float gamma0 = gamma[0];

  s16x8 qf0 = bc8(*reinterpret_cast<const u32x4*>(QT + ((size_t)b * NN + ibase + l16) * DQ + 8 * g));
  s16x8 qf1 = bc8(*reinterpret_cast<const u32x4*>(QT + ((size_t)b * NN + ibase + 16 + l16) * DQ + 8 * g));

  const unsigned _one2 = 0x3F803F80u;  // 2x bf16 1.0
  u32x4 _ones = {_one2, _one2, _one2, _one2};
  const s16x8 ones8 = bc8(_ones);

  f32x4 o[8][2];
  #pragma unroll
  for (int ct = 0; ct < 8; ++ct) { o[ct][0] = (f32x4){0,0,0,0}; o[ct][1] = (f32x4){0,0,0,0}; }
  f32x4 lsum0 = (f32x4){0,0,0,0}, lsum1 = (f32x4){0,0,0,0};
  float m0 = 8.0f, m1 = 8.0f;     // defer-max anchors (shift cancels exactly: 2^-8)
  const f32x4 zz = {0.f, 0.f, 0.f, 0.f};

  const unsigned short* Kbg = KT + (size_t)b * NN * DQ;
  const unsigned short* Vbg = Vm + (size_t)b * NN * CC;

  // staging coords: group of 256 threads stages 256 rows x 64B (4 b128 each)
  const int ltid = tid & 255;
  const int cL   = ltid >> 2;
  const int pcL  = ltid & 3;
  const int vwo  = cL * RS + pcL * 8;

  unsigned short* B0 = smem + (jh * 3 + 0) * BUFE;
  unsigned short* B1 = smem + (jh * 3 + 1) * BUFE;
  unsigned short* B2 = smem + (jh * 3 + 2) * BUFE;

  u32x4 vst0, vst1, vst2, vst3;
  u32x4 k0a, k0b, k1a, k1b, k2a, k2b;

  // Prologue: tile0 -> B0; vst holds tile1; K(0..2) in regs
  V_ISSUE(0);
  V_WRITE(B0);
  V_ISSUE(1);
  K_ISSUE(0, k0a, k0b);
  K_ISSUE(1, k1a, k1b);
  K_ISSUE(2, k2a, k2b);
  BAR();

  #pragma unroll 1
  for (int tt = 0; tt < 21; ++tt) {
    ITER(3 * tt,     B0, B1, k0a, k0b);
    ITER(3 * tt + 1, B1, B2, k1a, k1b);
    ITER(3 * tt + 2, B2, B0, k2a, k2b);
  }
  ITER(63, B0, B1, k0a, k0b);   // 63 = 3*21; k0 holds K(63) (refilled at t=60)

  // ---- merge the two j-halves through LDS (buffers no longer needed) ----
  float* fb = (float*)smem;
  const float lA0 = lsum0[0], lA1 = lsum1[0];   // every lane holds own-column l
  if (jh == 1) {
    f32x4* ob = (f32x4*)fb;
    #pragma unroll
    for (int ct = 0; ct < 8; ++ct) {
      ob[((((chv * 8 + ct) * 2 + 0) * 2) + s) * 64 + lane] = o[ct][0];
      ob[((((chv * 8 + ct) * 2 + 1) * 2) + s) * 64 + lane] = o[ct][1];
    }
    if (chv == 0 && g == 0) {
      fb[16384 + s * 32 + l16]      = m0;
      fb[16384 + s * 32 + 16 + l16] = m1;
      fb[16448 + s * 32 + l16]      = lA0;
      fb[16448 + s * 32 + 16 + l16] = lA1;
    }
  }
  BAR();
  if (jh == 0) {
    const float mB0 = fb[16384 + s * 32 + l16];
    const float mB1 = fb[16384 + s * 32 + 16 + l16];
    const float lB0 = fb[16448 + s * 32 + l16];
    const float lB1 = fb[16448 + s * 32 + 16 + l16];
    const float mS0 = fmaxf(m0, mB0), mS1 = fmaxf(m1, mB1);
    const float aA0 = exp2f(m0 - mS0), aB0 = exp2f(mB0 - mS0);
    const float aA1 = exp2f(m1 - mS1), aB1 = exp2f(mB1 - mS1);
    const float ga0 = gamma0 / (aA0 * lA0 + aB0 * lB0);
    const float ga1 = gamma0 / (aA1 * lA1 + aB1 * lB1);
    const f32x4* ob = (const f32x4*)fb;
    #pragma unroll
    for (int ct = 0; ct < 8; ++ct) {
      f32x4 oB0 = ob[((((chv * 8 + ct) * 2 + 0) * 2) + s) * 64 + lane];
      f32x4 oB1 = ob[((((chv * 8 + ct) * 2 + 1) * 2) + s) * 64 + lane];
      #pragma unroll
      for (int r = 0; r < 4; ++r) {
        const int c = chv * 128 + ct * 16 + 4 * g + r;
        const size_t a0 = ((size_t)b * CC + c) * NN + ibase + l16;
        const size_t a1 = a0 + 16;
        out[a0] = ga0 * (aA0 * o[ct][0][r] + aB0 * oB0[r]) + x[a0];
        out[a1] = ga1 * (aA1 * o[ct][1][r] + aB1 * oB1[r]) + x[a1];
      }
    }
  }
}

extern "C" void kernel_launch(void* const* d_in, const int* in_sizes, int n_in,
                              void* d_out, int out_size, void* d_ws, size_t ws_size,
                              hipStream_t stream) {
  const float* x     = (const float*)d_in[0];
  const float* Wq    = (const float*)d_in[1];
  const float* bq    = (const float*)d_in[2];
  const float* Wk    = (const float*)d_in[3];
  const float* bk    = (const float*)d_in[4];
  const float* Wv    = (const float*)d_in[5];
  const float* bv    = (const float*)d_in[6];
  const float* gamma = (const float*)d_in[7];
  float* out = (float*)d_out;

  unsigned short* QT = (unsigned short*)d_ws;
  unsigned short* KT = QT + (size_t)NB * NN * DQ;
  unsigned short* Vm = KT + (size_t)NB * NN * DQ;

  static bool attr_set = false;
  if (!attr_set) {
    hipFuncSetAttribute((const void*)attn_kernel,
                        hipFuncAttributeMaxDynamicSharedMemorySize, 6 * BUFE * 2);
    attr_set = true;
  }

  dim3 gridP(64, NB), blkP(256);
  proj_kernel<<<gridP, blkP, 0, stream>>>(x, Wq, bq, Wk, bk, Wv, bv, QT, KT, Vm);
  attn_kernel<<<256, 512, 6 * BUFE * 2, stream>>>(QT, KT, Vm, x, gamma, out);
}

// Round 6
// 87.358 us; speedup vs baseline: 5.6938x; 1.1130x over previous
//
#include <hip/hip_runtime.h>

#define NN 4096   // H*W
#define CC 256    // channels
#define DQ 32     // d_qk
#define NB 4      // batch

typedef float        f32x4  __attribute__((ext_vector_type(4)));
typedef float        f32x16 __attribute__((ext_vector_type(16)));
typedef short        s16x4  __attribute__((ext_vector_type(4)));
typedef short        s16x8  __attribute__((ext_vector_type(8)));
typedef unsigned int u32x2  __attribute__((ext_vector_type(2)));
typedef unsigned int u32x4  __attribute__((ext_vector_type(4)));

// float -> bf16 bits, round-to-nearest-even
__device__ __forceinline__ unsigned short f2bf(float f) {
  unsigned u = __builtin_bit_cast(unsigned, f);
  u += 0x7fffu + ((u >> 16) & 1u);
  return (unsigned short)(u >> 16);
}

__device__ __forceinline__ f32x4 mfma16(s16x4 a, s16x4 b, f32x4 c) {
  return __builtin_amdgcn_mfma_f32_16x16x16bf16_1k(a, b, c, 0, 0, 0);
}
__device__ __forceinline__ f32x16 mfma32b(s16x8 a, s16x8 b, f32x16 c) {
  return __builtin_amdgcn_mfma_f32_32x32x16_bf16(a, b, c, 0, 0, 0);
}

__device__ __forceinline__ s16x4 lo4(u32x4 r) { u32x2 t = {r[0], r[1]}; return __builtin_bit_cast(s16x4, t); }
__device__ __forceinline__ s16x4 hi4(u32x4 r) { u32x2 t = {r[2], r[3]}; return __builtin_bit_cast(s16x4, t); }
__device__ __forceinline__ s16x8 bc8(u32x4 r) { return __builtin_bit_cast(s16x8, r); }

#define XLS 264   // proj LDS row stride (256 + 8 pad)

// ---------------- Kernel A: fused QKV projection ----------------
// QT/KT: [B][N][32] bf16 row-contiguous (natural d-order).
// Vm   : TILED [B][jt=N/32][C][32] bf16; within-32 order pos(j) matches the
//        32x32x16 MFMA C->B register bijection:
//        pos(j) = (j&3) + 4*((j>>3)&1) + 8*((j>>2)&1) + 16*((j>>4)&1)
__global__ __launch_bounds__(256)
void proj_kernel(const float* __restrict__ x,
                 const float* __restrict__ Wq, const float* __restrict__ bq,
                 const float* __restrict__ Wk, const float* __restrict__ bk,
                 const float* __restrict__ Wv, const float* __restrict__ bv,
                 unsigned short* __restrict__ QT,
                 unsigned short* __restrict__ KT,
                 unsigned short* __restrict__ Vm) {
  __shared__ unsigned short Xl[64 * XLS];
  const int tid = threadIdx.x;
  const int b   = blockIdx.y;
  const int n0  = blockIdx.x * 64;

  {
    const int n4 = (tid & 15) * 4;
    int c = tid >> 4;
    const float* xp = x + (size_t)(b * CC + c) * NN + n0 + n4;
    #pragma unroll
    for (int it = 0; it < 16; ++it) {
      f32x4 v = *reinterpret_cast<const f32x4*>(xp);
      #pragma unroll
      for (int e = 0; e < 4; ++e)
        Xl[(n4 + e) * XLS + c] = f2bf(v[e]);
      c += 16; xp += (size_t)16 * NN;
    }
  }
  __syncthreads();

  const int wave = tid >> 6;
  const int lane = tid & 63;
  const int l16  = lane & 15;
  const int g    = lane >> 4;
  const float qscale = 0.0901684400555602f;  // log2(e)/16

  const float* wrowp[5];
  float wsc[5];
  #pragma unroll
  for (int rt = 0; rt < 5; ++rt) {
    const int R0 = (wave * 5 + rt) * 16;
    const int R  = R0 + l16;
    if (R0 < 32)      { wrowp[rt] = Wq + R * CC;        wsc[rt] = qscale; }
    else if (R0 < 64) { wrowp[rt] = Wk + (R - 32) * CC; wsc[rt] = 1.0f; }
    else              { wrowp[rt] = Wv + (R - 64) * CC; wsc[rt] = 1.0f; }
  }

  f32x4 acc[5][4];
  #pragma unroll
  for (int rt = 0; rt < 5; ++rt)
    #pragma unroll
    for (int nt = 0; nt < 4; ++nt) acc[rt][nt] = (f32x4){0.f, 0.f, 0.f, 0.f};

  for (int k0 = 0; k0 < CC; k0 += 32) {
    s16x4 xb[4][2];
    #pragma unroll
    for (int nt = 0; nt < 4; ++nt) {
      const unsigned short* p = &Xl[(l16 + 16 * nt) * XLS + k0 + 8 * g];
      u32x4 raw = *reinterpret_cast<const u32x4*>(p);
      xb[nt][0] = lo4(raw);
      xb[nt][1] = hi4(raw);
    }
    #pragma unroll
    for (int rt = 0; rt < 5; ++rt) {
      const float* wp = wrowp[rt] + k0 + 8 * g;
      f32x4 w0 = *reinterpret_cast<const f32x4*>(wp);
      f32x4 w1 = *reinterpret_cast<const f32x4*>(wp + 4);
      const float sc = wsc[rt];
      s16x4 wa0, wa1;
      #pragma unroll
      for (int e = 0; e < 4; ++e) {
        wa0[e] = (short)f2bf(w0[e] * sc);
        wa1[e] = (short)f2bf(w1[e] * sc);
      }
      #pragma unroll
      for (int nt = 0; nt < 4; ++nt) {
        acc[rt][nt] = mfma16(wa0, xb[nt][0], acc[rt][nt]);
        acc[rt][nt] = mfma16(wa1, xb[nt][1], acc[rt][nt]);
      }
    }
  }

  #pragma unroll
  for (int rt = 0; rt < 5; ++rt) {
    const int R0 = (wave * 5 + rt) * 16;
    float bias_r[4];
    {
      const float* bp; float bsc;
      if (R0 < 32)      { bp = bq + R0;      bsc = qscale; }
      else if (R0 < 64) { bp = bk + R0 - 32; bsc = 1.0f; }
      else              { bp = bv + R0 - 64; bsc = 1.0f; }
      #pragma unroll
      for (int r = 0; r < 4; ++r) bias_r[r] = bp[4 * g + r] * bsc;
    }
    #pragma unroll
    for (int nt = 0; nt < 4; ++nt) {
      const int n = n0 + nt * 16 + l16;
      float v0 = acc[rt][nt][0] + bias_r[0];
      float v1 = acc[rt][nt][1] + bias_r[1];
      float v2 = acc[rt][nt][2] + bias_r[2];
      float v3 = acc[rt][nt][3] + bias_r[3];
      if (R0 < 64) {
        u32x2 pk = { (unsigned)f2bf(v0) | ((unsigned)f2bf(v1) << 16),
                     (unsigned)f2bf(v2) | ((unsigned)f2bf(v3) << 16) };
        unsigned short* dst = (R0 < 32)
          ? (QT + ((size_t)b * NN + n) * DQ + R0 + 4 * g)
          : (KT + ((size_t)b * NN + n) * DQ + (R0 - 32) + 4 * g);
        *reinterpret_cast<u32x2*>(dst) = pk;
      } else {
        // j within tile = 16*(nt&1) + l16; pos = 32x32-bijection order
        const int c0  = R0 - 64 + 4 * g;
        const int jt  = (n0 + nt * 16) >> 5;
        const int pos = (l16 & 3) + 4 * ((l16 >> 3) & 1) + 8 * ((l16 >> 2) & 1)
                      + 16 * (nt & 1);
        unsigned short* vd = Vm + ((size_t)(b * 128 + jt) * CC + c0) * 32 + pos;
        vd[0]  = f2bf(v0);
        vd[32] = f2bf(v1);
        vd[64] = f2bf(v2);
        vd[96] = f2bf(v3);
      }
    }
  }
}

// ---------------- Kernel B: flash attention, 32x32 MFMA, fixed anchor ----------------
// 8 waves = 2 strips(32 q) x 2 c-halves(128 ch) x 2 j-halves.
// Per wave-tile: 2 QK MFMA-32 + 8 PV MFMA-32, 8 ds_read_b128 + 4 ds_write_b128,
// 16 exp2, 8 cvt_pk, P feeds PV straight from registers (C->B bijection).
// LDS: rows 64B exact, col-XOR swizzle (q ^ ((row>>1)&3)) both sides.
#define BUFE (256 * 32)   // elems per V buffer (16 KB)

#define V_ISSUE(TL) { \
  const unsigned short* _s = Vbg + ((size_t)(jh * 64 + (TL)) * CC + cL) * 32 + pcL * 8; \
  vst0 = *(const u32x4*)(_s); \
  vst1 = *(const u32x4*)(_s + 64 * 32); \
  vst2 = *(const u32x4*)(_s + 128 * 32); \
  vst3 = *(const u32x4*)(_s + 192 * 32); }

#define V_WRITE(BUF) { \
  *(u32x4*)&(BUF)[vwo]            = vst0; \
  *(u32x4*)&(BUF)[vwo + 64 * 32]  = vst1; \
  *(u32x4*)&(BUF)[vwo + 128 * 32] = vst2; \
  *(u32x4*)&(BUF)[vwo + 192 * 32] = vst3; }

#define K_ISSUE(TL, KA, KB) { \
  const unsigned short* _k = Kbg + (size_t)((jh * 64 + (TL)) * 32 + l31) * DQ; \
  KA = *(const u32x4*)(_k + 8 * g2); \
  KB = *(const u32x4*)(_k + 16 + 8 * g2); }

// raw barrier: drain LDS ops, keep global prefetch loads in flight
#define BAR() { asm volatile("s_waitcnt lgkmcnt(0)" ::: "memory"); __builtin_amdgcn_s_barrier(); }

#define ITER(TL, CUR, NXT, KA, KB) { \
  V_WRITE(NXT); \
  f32x16 ss = mfma32b(bc8(KA), qf0, zz16); \
  ss = mfma32b(bc8(KB), qf1, ss); \
  { const int _tp = ((TL) + 2 < 64) ? (TL) + 2 : 63; V_ISSUE(_tp); } \
  { const int _tk = ((TL) + 3 < 64) ? (TL) + 3 : 63; K_ISSUE(_tk, KA, KB); } \
  const float p0  = exp2f(ss[0]),  p1  = exp2f(ss[1]),  p2  = exp2f(ss[2]),  p3  = exp2f(ss[3]); \
  const float p4  = exp2f(ss[4]),  p5  = exp2f(ss[5]),  p6  = exp2f(ss[6]),  p7  = exp2f(ss[7]); \
  const float p8  = exp2f(ss[8]),  p9  = exp2f(ss[9]),  p10 = exp2f(ss[10]), p11 = exp2f(ss[11]); \
  const float p12 = exp2f(ss[12]), p13 = exp2f(ss[13]), p14 = exp2f(ss[14]), p15 = exp2f(ss[15]); \
  l_run += (((p0 + p1) + (p2 + p3)) + ((p4 + p5) + (p6 + p7))) \
         + (((p8 + p9) + (p10 + p11)) + ((p12 + p13) + (p14 + p15))); \
  unsigned a0, a1, a2, a3, b0, b1, b2, b3; \
  asm("v_cvt_pk_bf16_f32 %0, %1, %2" : "=v"(a0) : "v"(p0),  "v"(p1)); \
  asm("v_cvt_pk_bf16_f32 %0, %1, %2" : "=v"(a1) : "v"(p2),  "v"(p3)); \
  asm("v_cvt_pk_bf16_f32 %0, %1, %2" : "=v"(a2) : "v"(p4),  "v"(p5)); \
  asm("v_cvt_pk_bf16_f32 %0, %1, %2" : "=v"(a3) : "v"(p6),  "v"(p7)); \
  asm("v_cvt_pk_bf16_f32 %0, %1, %2" : "=v"(b0) : "v"(p8),  "v"(p9)); \
  asm("v_cvt_pk_bf16_f32 %0, %1, %2" : "=v"(b1) : "v"(p10), "v"(p11)); \
  asm("v_cvt_pk_bf16_f32 %0, %1, %2" : "=v"(b2) : "v"(p12), "v"(p13)); \
  asm("v_cvt_pk_bf16_f32 %0, %1, %2" : "=v"(b3) : "v"(p14), "v"(p15)); \
  u32x4 _pk0 = {a0, a1, a2, a3}; \
  u32x4 _pk1 = {b0, b1, b2, b3}; \
  const s16x8 P0 = bc8(_pk0); \
  const s16x8 P1 = bc8(_pk1); \
  BAR(); /* NXT visible; CUR was published by previous BAR */ \
  __builtin_amdgcn_s_setprio(1); \
  _Pragma("unroll") \
  for (int ct = 0; ct < 4; ++ct) { \
    u32x4 _va = *(const u32x4*)&(CUR)[rbase0 + ct * 1024]; \
    u32x4 _vb = *(const u32x4*)&(CUR)[rbase1 + ct * 1024]; \
    o[ct] = mfma32b(bc8(_va), P0, o[ct]); \
    o[ct] = mfma32b(bc8(_vb), P1, o[ct]); \
  } \
  __builtin_amdgcn_s_setprio(0); \
}

__global__ __launch_bounds__(512)
void attn_kernel(const unsigned short* __restrict__ QT,
                 const unsigned short* __restrict__ KT,
                 const unsigned short* __restrict__ Vm,
                 const float* __restrict__ x,
                 const float* __restrict__ gamma,
                 float* __restrict__ out) {
  extern __shared__ unsigned short smem[];

  const int tid  = threadIdx.x;
  const int wave = tid >> 6;
  const int lane = tid & 63;
  const int l31  = lane & 31;
  const int g2   = lane >> 5;
  const int jh   = wave >> 2;        // j-half
  const int s    = (wave >> 1) & 1;  // strip (32 q-rows)
  const int chv  = wave & 1;         // channel half (128 ch)

  // XCD swizzle: gid%8 -> XCD; one batch per XCD pair
  const int gid = blockIdx.x;
  const int rr  = gid & 7;
  const int qq  = gid >> 3;
  const int b   = rr >> 1;
  const int xt  = (qq << 1) | (rr & 1);

  const int ibase = xt * 64 + s * 32;
  const int i     = ibase + l31;
  const float gamma0 = gamma[0];

  const s16x8 qf0 = bc8(*reinterpret_cast<const u32x4*>(QT + ((size_t)b * NN + i) * DQ + 8 * g2));
  const s16x8 qf1 = bc8(*reinterpret_cast<const u32x4*>(QT + ((size_t)b * NN + i) * DQ + 16 + 8 * g2));

  f32x16 o[4];
  #pragma unroll
  for (int ct = 0; ct < 4; ++ct)
    #pragma unroll
    for (int r = 0; r < 16; ++r) o[ct][r] = 0.f;
  float l_run = 0.f;
  f32x16 zz16;
  #pragma unroll
  for (int r = 0; r < 16; ++r) zz16[r] = 0.f;

  const unsigned short* Kbg = KT + (size_t)b * NN * DQ;
  const unsigned short* Vbg = Vm + (size_t)b * NN * CC;

  // staging coords: 256 threads stage 256 rows x 64B; col-XOR swizzle on write
  const int ltid = tid & 255;
  const int cL   = ltid >> 2;
  const int pcL  = ltid & 3;
  const int vwo  = cL * 32 + ((pcL ^ ((cL >> 1) & 3)) * 8);

  // read bases (elems), lane-constant XOR swizzle (matches write side)
  const int swR    = (l31 >> 1) & 3;
  const int rbase0 = (chv * 128 + l31) * 32 + ((g2 ^ swR) * 8);
  const int rbase1 = (chv * 128 + l31) * 32 + (((2 + g2) ^ swR) * 8);

  unsigned short* B0 = smem + (jh * 3 + 0) * BUFE;
  unsigned short* B1 = smem + (jh * 3 + 1) * BUFE;
  unsigned short* B2 = smem + (jh * 3 + 2) * BUFE;

  u32x4 vst0, vst1, vst2, vst3;
  u32x4 k0a, k0b, k1a, k1b, k2a, k2b;

  V_ISSUE(0);
  V_WRITE(B0);
  V_ISSUE(1);
  K_ISSUE(0, k0a, k0b);
  K_ISSUE(1, k1a, k1b);
  K_ISSUE(2, k2a, k2b);
  BAR();

  #pragma unroll 1
  for (int tt = 0; tt < 21; ++tt) {
    ITER(3 * tt,     B0, B1, k0a, k0b);
    ITER(3 * tt + 1, B1, B2, k1a, k1b);
    ITER(3 * tt + 2, B2, B0, k2a, k2b);
  }
  ITER(63, B0, B1, k0a, k0b);

  // Drain ALL waves' final PV ds_reads before the merge phase overwrites the
  // V buffers (fb aliases B0..B2). R5's missing barrier here was a race: the
  // mid-ITER BAR lets the last PV reads run concurrently with fb writes.
  BAR();

  // complete the denominator: other 16 j's live in the opposite g2 half
  l_run += __shfl_xor(l_run, 32);

  // ---- merge the two j-halves (fixed anchor -> plain adds) ----
  float* fb = (float*)smem;
  const int slot = (s * 2 + chv) * 4;
  if (jh == 1) {
    #pragma unroll
    for (int ct = 0; ct < 4; ++ct)
      #pragma unroll
      for (int r = 0; r < 16; ++r)
        fb[((slot + ct) * 16 + r) * 64 + lane] = o[ct][r];
    if (chv == 0 && g2 == 0)
      fb[16384 + s * 32 + l31] = l_run;
  }
  BAR();
  if (jh == 0) {
    const float lB = fb[16384 + s * 32 + l31];
    const float ga = gamma0 / (l_run + lB);
    #pragma unroll
    for (int ct = 0; ct < 4; ++ct) {
      #pragma unroll
      for (int r = 0; r < 16; ++r) {
        const float oB = fb[((slot + ct) * 16 + r) * 64 + lane];
        const int   c  = chv * 128 + ct * 32 + (r & 3) + 8 * (r >> 2) + 4 * g2;
        const size_t adr = ((size_t)b * CC + c) * NN + i;
        out[adr] = ga * (o[ct][r] + oB) + x[adr];
      }
    }
  }
}

extern "C" void kernel_launch(void* const* d_in, const int* in_sizes, int n_in,
                              void* d_out, int out_size, void* d_ws, size_t ws_size,
                              hipStream_t stream) {
  const float* x     = (const float*)d_in[0];
  const float* Wq    = (const float*)d_in[1];
  const float* bq    = (const float*)d_in[2];
  const float* Wk    = (const float*)d_in[3];
  const float* bk    = (const float*)d_in[4];
  const float* Wv    = (const float*)d_in[5];
  const float* bv    = (const float*)d_in[6];
  const float* gamma = (const float*)d_in[7];
  float* out = (float*)d_out;

  unsigned short* QT = (unsigned short*)d_ws;
  unsigned short* KT = QT + (size_t)NB * NN * DQ;
  unsigned short* Vm = KT + (size_t)NB * NN * DQ;

  static bool attr_set = false;
  if (!attr_set) {
    hipFuncSetAttribute((const void*)attn_kernel,
                        hipFuncAttributeMaxDynamicSharedMemorySize, 6 * BUFE * 2);
    attr_set = true;
  }

  dim3 gridP(64, NB), blkP(256);
  proj_kernel<<<gridP, blkP, 0, stream>>>(x, Wq, bq, Wk, bk, Wv, bv, QT, KT, Vm);
  attn_kernel<<<256, 512, 6 * BUFE * 2, stream>>>(QT, KT, Vm, x, gamma, out);
}